// Round 6
// baseline (93.024 us; speedup 1.0000x reference)
//
#include <hip/hip_runtime.h>
#include <math.h>

#define B_ 2
#define M_ 384
#define N_ 384
#define NTY 10            // padded theta rows
#define NSLOT 640         // 40 cells x 16 f
#define QN 96             // field points per accumulation block
#define NQ 4              // quarters per (b,m)

// Inline minimax atan2 (max err ~1e-5 rad; output threshold 0.115, we're at 0.004)
__device__ __forceinline__ float fast_atan2f(float y, float x) {
  float ax = fabsf(x), ay = fabsf(y);
  float mx = fmaxf(ax, ay), mn = fminf(ax, ay);
  float a = mn * __builtin_amdgcn_rcpf(mx);
  if (mx == 0.f) a = 0.f;
  float s = a * a;
  float p = -0.0117212f;
  p = fmaf(p, s, 0.05265332f);
  p = fmaf(p, s, -0.11643287f);
  p = fmaf(p, s, 0.19354346f);
  p = fmaf(p, s, -0.33262347f);
  p = fmaf(p, s, 0.99997726f);
  float r = p * a;
  if (ay > ax) r = 1.57079632679f - r;
  if (x < 0.f) r = 3.14159265359f - r;
  return (y < 0.f) ? -r : r;
}

// K1: one WAVE per (b,m,quarter). No barriers, no atomics.
//   ballot-compact active n's into LDS, then lane=(f,xr) gathers with 10
//   register accumulators; coalesced S-partial store to d_ws.
__global__ __launch_bounds__(64) void accum_kernel(
    const float* __restrict__ field,   // [B][N][2]
    const float* __restrict__ center,  // [B][M][2]
    const float* __restrict__ feat,    // [B][N][8][2]
    const float* __restrict__ mask,    // [B][N][1]
    float* __restrict__ wsS,           // [3072][640]
    float* __restrict__ wsPsi) {       // [3072]
  __shared__ float4 sMeta[QN];         // {bits(fn,x0,y0), att, wx, wy}

  int t = threadIdx.x;                 // lane 0..63
  int blk = blockIdx.x;                // 0..3071
  int bm = blk >> 2, q = blk & 3;
  int b = bm / M_;

  float cx = center[bm * 2 + 0];
  float cy = center[bm * 2 + 1];
  const float invR = 1.0f / 1.5f;
  const float fourpi = 4.0f / 3.14159265358979323846f;
  float psi = 0.f;
  int cnt = 0;

#pragma unroll
  for (int r = 0; r < 2; ++r) {
    int off = r * 64 + t;
    bool elig = off < QN;              // round 1: lanes 0..31 only
    int n = q * QN + (elig ? off : 0);
    int fn = b * N_ + n;
    float2 fxy = ((const float2*)field)[fn];
    float msk = mask[fn];
    float rx = (fxy.x - cx) * invR;
    float ry = (fxy.y - cy) * invR;
    float r2 = rx * rx + ry * ry;
    float onem = 1.f - r2;
    float attr = onem * onem * onem;
    float att = attr * msk;
    float rr = sqrtf(r2 + 1e-9f);
    float theta = fast_atan2f(ry, rx);
    float ix = 4.f * rr - 0.5f;                // x0 in {-1..3}
    float iy = theta * fourpi + 4.5f;          // y0 in {0..8}
    float x0f = floorf(ix), y0f = floorf(iy);
    int x0 = (int)x0f, y0 = (int)y0f;

    bool pred = elig && (attr > 0.f) && (att != 0.f);
    unsigned long long bmask = __ballot(pred);
    int pos = cnt + __popcll(bmask & ((1ull << t) - 1ull));
    if (pred) {
      int meta = fn | ((x0 + 1) << 12) | (y0 << 16);
      sMeta[pos] = make_float4(__int_as_float(meta), att, ix - x0f, iy - y0f);
      psi += att;
    }
    cnt += __popcll(bmask);
  }

  // gather phase: lane = (f, xr), 10 ty-cells in registers
  int f  = t & 15;
  int xr = t >> 4;
  float acc[NTY];
#pragma unroll
  for (int k = 0; k < NTY; ++k) acc[k] = 0.f;

#pragma unroll 2
  for (int a = 0; a < cnt; ++a) {
    float4 md = sMeta[a];              // wave-uniform broadcast read
    int meta = __float_as_int(md.x);
    int fn = meta & 0xFFF;
    float g = feat[fn * 16 + f] * md.y;  // one 64B line per wave-load
    int x0 = ((meta >> 12) & 7) - 1;
    int y0 = (meta >> 16) & 15;
    float wx1 = md.z, wy1 = md.w;
    float ux = (xr == x0) ? (1.f - wx1) : ((xr == x0 + 1) ? wx1 : 0.f);
    float ug = ux * g;
    float wy0 = 1.f - wy1;
#pragma unroll
    for (int k = 0; k < NTY; ++k) {
      float vy = (k == y0) ? wy0 : ((k == y0 + 1) ? wy1 : 0.f);
      acc[k] = fmaf(vy, ug, acc[k]);
    }
  }

  // coalesced partial store: slot (k*4+xr)*16+f == k*64 + t
  float* Sp = wsS + blk * NSLOT;
#pragma unroll
  for (int k = 0; k < NTY; ++k) Sp[k * 64 + t] = acc[k];

#pragma unroll
  for (int off = 32; off > 0; off >>= 1) psi += __shfl_xor(psi, off, 64);
  if (t == 0) wsPsi[blk] = psi;
}

// K2: combine 4 quarter-partials, contract against kern, divide by psi.
__global__ __launch_bounds__(256) void finish_kernel(
    const float* __restrict__ wsS,
    const float* __restrict__ wsPsi,
    const float* __restrict__ kern,    // [8][8][4][8][2][2]
    float* __restrict__ out) {         // [B][M][8][2]
  __shared__ float sS[NSLOT];
  __shared__ float sPartial[16][17];
  __shared__ float sPsi4[NQ];

  int t = threadIdx.x;
  int bm = blockIdx.x;

  if (t < NQ) sPsi4[t] = wsPsi[bm * NQ + t];
  const float* p = wsS + bm * NQ * NSLOT;
  for (int s = t; s < NSLOT; s += 256)
    sS[s] = p[s] + p[NSLOT + s] + p[2 * NSLOT + s] + p[3 * NSLOT + s];
  __syncthreads();

  int oy = t & 15, grp = t >> 4;
  int o = oy >> 1, y = oy & 1;
  float cacc = 0.f;
  for (int c = grp; c < 40; c += 16) {
    int ty = c >> 2, cxr = c & 3;
    int th = (ty + 7) & 7;             // circular theta pad
    const float* sp = &sS[c * 16];
#pragma unroll
    for (int ff = 0; ff < 16; ++ff) {
      int i = ff >> 1, x = ff & 1;
      int idx = ((((o * 8 + i) * 4 + cxr) * 8 + th) * 2 + y) * 2 + x;
      cacc = fmaf(kern[idx], sp[ff], cacc);
    }
  }
  sPartial[grp][oy] = cacc;
  __syncthreads();

  if (t < 16) {
    float sum = 0.f;
#pragma unroll
    for (int gg = 0; gg < 16; ++gg) sum += sPartial[gg][t];
    float psi = sPsi4[0] + sPsi4[1] + sPsi4[2] + sPsi4[3];
    if (psi == 0.f) psi = 1.f;
    out[bm * 16 + t] = sum / psi;
  }
}

extern "C" void kernel_launch(void* const* d_in, const int* in_sizes, int n_in,
                              void* d_out, int out_size, void* d_ws, size_t ws_size,
                              hipStream_t stream) {
  (void)in_sizes; (void)n_in; (void)out_size; (void)ws_size;
  const float* field  = (const float*)d_in[0];
  const float* center = (const float*)d_in[1];
  const float* feat   = (const float*)d_in[2];
  const float* mask   = (const float*)d_in[3];
  const float* kern   = (const float*)d_in[4];
  float* out = (float*)d_out;
  float* wsS = (float*)d_ws;                         // 3072*640 floats
  float* wsPsi = wsS + (B_ * M_ * NQ) * NSLOT;       // +3072 floats

  accum_kernel<<<dim3(B_ * M_ * NQ), dim3(64), 0, stream>>>(
      field, center, feat, mask, wsS, wsPsi);
  finish_kernel<<<dim3(B_ * M_), dim3(256), 0, stream>>>(
      wsS, wsPsi, kern, out);
}

// Round 7
// 83.366 us; speedup vs baseline: 1.1159x; 1.1159x over previous
//
#include <hip/hip_runtime.h>
#include <math.h>

#define B_ 2
#define M_ 384
#define N_ 384
#define NTY 10            // padded theta rows
#define NSLOT 640         // 40 cells x 16 f
#define WN 96             // field points per wave (4 waves x 96 = 384)

// Inline minimax atan2 (max err ~1e-5 rad; output threshold 0.115, we're at 0.004)
__device__ __forceinline__ float fast_atan2f(float y, float x) {
  float ax = fabsf(x), ay = fabsf(y);
  float mx = fmaxf(ax, ay), mn = fminf(ax, ay);
  float a = mn * __builtin_amdgcn_rcpf(mx);
  if (mx == 0.f) a = 0.f;
  float s = a * a;
  float p = -0.0117212f;
  p = fmaf(p, s, 0.05265332f);
  p = fmaf(p, s, -0.11643287f);
  p = fmaf(p, s, 0.19354346f);
  p = fmaf(p, s, -0.33262347f);
  p = fmaf(p, s, 0.99997726f);
  float r = p * a;
  if (ay > ax) r = 1.57079632679f - r;
  if (x < 0.f) r = 3.14159265359f - r;
  return (y < 0.f) ? -r : r;
}

// One block per (b,m), 4 waves. Each wave fully independent until one
// barrier before the final reduce: wave-private ballot compaction (no
// atomics), wave-private LDS segments (no A->B barrier: same-wave LDS
// ordering is guaranteed by lgkmcnt), register-accumulator gather.
__global__ __launch_bounds__(256) void equiconv_kernel(
    const float* __restrict__ field,   // [B][N][2]
    const float* __restrict__ center,  // [B][M][2]
    const float* __restrict__ feat,    // [B][N][8][2] -> 16 per n
    const float* __restrict__ mask,    // [B][N][1]
    const float* __restrict__ kern,    // [8][8][4][8][2][2] = 8192 floats
    float* __restrict__ out) {         // [B][M][8][2] -> 16 per (b,m)
  __shared__ float4 sMeta[4][WN];      // {bits(x0,y0), wx, wy, -} per wave
  __shared__ float4 sG4[4][WN * 4];    // att*feat, 16 floats per active
  __shared__ float  sS4[4][NSLOT];     // per-wave partial S
  __shared__ float  sS[NSLOT];
  __shared__ float  sPartial[16][17];
  __shared__ float  sPsi[4];

  int t = threadIdx.x;
  int lane = t & 63;
  int w = t >> 6;
  int bm = blockIdx.x;
  int b = bm / M_;

  // ---- Phase A: geometry + wave-private ballot compaction ----
  float cx = center[bm * 2 + 0];
  float cy = center[bm * 2 + 1];
  const float invR = 1.0f / 1.5f;
  const float fourpi = 4.0f / 3.14159265358979323846f;
  float psi = 0.f;
  int cnt = 0;

#pragma unroll
  for (int r = 0; r < 2; ++r) {
    int off = r * 64 + lane;
    bool elig = off < WN;              // r=1: lanes 0..31 only
    int n = w * WN + (elig ? off : 0);
    int fn = b * N_ + n;
    float2 fxy = ((const float2*)field)[fn];
    float msk = mask[fn];
    const float4* fp = (const float4*)(feat + fn * 16);
    float4 f0 = fp[0], f1 = fp[1], f2 = fp[2], f3 = fp[3];  // speculative

    float rx = (fxy.x - cx) * invR;
    float ry = (fxy.y - cy) * invR;
    float r2 = rx * rx + ry * ry;
    float onem = 1.f - r2;
    float attr = onem * onem * onem;
    float att = attr * msk;

    float rr = sqrtf(r2 + 1e-9f);
    float theta = fast_atan2f(ry, rx);
    float ix = 4.f * rr - 0.5f;                // x0 in {-1..3}
    float iy = theta * fourpi + 4.5f;          // y0 in {0..8}
    float x0f = floorf(ix), y0f = floorf(iy);
    int x0 = (int)x0f, y0 = (int)y0f;

    bool pred = elig && (attr > 0.f) && (att != 0.f);
    unsigned long long bmask = __ballot(pred);
    int pos = cnt + __popcll(bmask & ((1ull << lane) - 1ull));
    if (pred) {
      psi += att;
      sMeta[w][pos] = make_float4(
          __int_as_float((x0 + 1) | (y0 << 8)), ix - x0f, iy - y0f, 0.f);
      float4* gp = &sG4[w][pos * 4];
      f0.x *= att; f0.y *= att; f0.z *= att; f0.w *= att;
      f1.x *= att; f1.y *= att; f1.z *= att; f1.w *= att;
      f2.x *= att; f2.y *= att; f2.z *= att; f2.w *= att;
      f3.x *= att; f3.y *= att; f3.z *= att; f3.w *= att;
      gp[0] = f0; gp[1] = f1; gp[2] = f2; gp[3] = f3;
    }
    cnt += __popcll(bmask);
  }

#pragma unroll
  for (int off = 32; off > 0; off >>= 1) psi += __shfl_xor(psi, off, 64);
  if (lane == 0) sPsi[w] = psi;

  // ---- Phase B: wave-private gather (no barrier needed: same-wave LDS) ----
  int f  = lane & 15;
  int xr = lane >> 4;
  const float* sGf = (const float*)&sG4[w][0];

  float acc[NTY];
#pragma unroll
  for (int k = 0; k < NTY; ++k) acc[k] = 0.f;

#pragma unroll 2
  for (int a = 0; a < cnt; ++a) {
    float4 md = sMeta[w][a];             // b128 broadcast read
    float g = sGf[a * 16 + f];           // 16 consecutive words, 4-way bcast
    int meta = __float_as_int(md.x);
    int x0 = (meta & 255) - 1;
    int y0 = meta >> 8;
    float wx1 = md.y, wy1 = md.z;
    float ux = (xr == x0) ? (1.f - wx1) : ((xr == x0 + 1) ? wx1 : 0.f);
    float ug = ux * g;
    float wy0 = 1.f - wy1;
#pragma unroll
    for (int k = 0; k < NTY; ++k) {
      float vy = (k == y0) ? wy0 : ((k == y0 + 1) ? wy1 : 0.f);
      acc[k] = fmaf(vy, ug, acc[k]);
    }
  }
#pragma unroll
  for (int k = 0; k < NTY; ++k)
    sS4[w][k * 64 + lane] = acc[k];      // slot (k*4+xr)*16+f == k*64+lane
  __syncthreads();                       // the only cross-wave barrier pre-C

  // ---- Phase C: cross-wave reduce + contraction + output ----
  for (int s = t; s < NSLOT; s += 256)
    sS[s] = sS4[0][s] + sS4[1][s] + sS4[2][s] + sS4[3][s];
  __syncthreads();

  {
    int oy = t & 15, grp = t >> 4;
    int o = oy >> 1, y = oy & 1;
    float cacc = 0.f;
    for (int c = grp; c < 40; c += 16) {
      int ty = c >> 2, cxr = c & 3;
      int th = (ty + 7) & 7;             // circular theta pad
      const float* sp = &sS[c * 16];
#pragma unroll
      for (int ff = 0; ff < 16; ++ff) {
        int i = ff >> 1, x = ff & 1;
        int idx = ((((o * 8 + i) * 4 + cxr) * 8 + th) * 2 + y) * 2 + x;
        cacc = fmaf(kern[idx], sp[ff], cacc);
      }
    }
    sPartial[grp][oy] = cacc;
  }
  __syncthreads();

  if (t < 16) {
    float sum = 0.f;
#pragma unroll
    for (int gg = 0; gg < 16; ++gg) sum += sPartial[gg][t];
    float p4 = sPsi[0] + sPsi[1] + sPsi[2] + sPsi[3];
    if (p4 == 0.f) p4 = 1.f;
    out[bm * 16 + t] = sum / p4;
  }
}

extern "C" void kernel_launch(void* const* d_in, const int* in_sizes, int n_in,
                              void* d_out, int out_size, void* d_ws, size_t ws_size,
                              hipStream_t stream) {
  (void)in_sizes; (void)n_in; (void)out_size; (void)d_ws; (void)ws_size;
  const float* field  = (const float*)d_in[0];
  const float* center = (const float*)d_in[1];
  const float* feat   = (const float*)d_in[2];
  const float* mask   = (const float*)d_in[3];
  const float* kern   = (const float*)d_in[4];
  float* out = (float*)d_out;

  equiconv_kernel<<<dim3(B_ * M_), dim3(256), 0, stream>>>(
      field, center, feat, mask, kern, out);
}